// Round 8
// baseline (367.102 us; speedup 1.0000x reference)
//
#include <hip/hip_runtime.h>
#include <math.h>

#define N_NODES 50000
#define PAD_ROWS 50048                 // 1564 * 32
#define E_RAW   400000
#define E_TOT   (E_RAW + N_NODES)      // 450000 incl. self loops
#define NEG_SLOPE 0.2f

typedef __bf16 bf16_t;
typedef bf16_t bf16x8 __attribute__((ext_vector_type(8)));
typedef bf16_t bf16x4 __attribute__((ext_vector_type(4)));
typedef float  f32x4  __attribute__((ext_vector_type(4)));

__device__ __forceinline__ void fma4(float4& a, float s, const float4& w) {
    a.x += s * w.x; a.y += s * w.y; a.z += s * w.z; a.w += s * w.w;
}

// ---------------- CSR build ----------------

__global__ void k_hist(const int* __restrict__ ei, int* __restrict__ cnt) {
    int e = blockIdx.x * 256 + threadIdx.x;
    if (e >= E_TOT) return;
    int dst = (e < E_RAW) ? ei[E_RAW + e] : (e - E_RAW);
    atomicAdd(&cnt[dst], 1);
}

__global__ void k_scan1(const int* __restrict__ cnt, int* __restrict__ offs,
                        int* __restrict__ bsum) {
    __shared__ int s[256];
    int i = blockIdx.x * 256 + threadIdx.x;
    int v = (i < N_NODES) ? cnt[i] : 0;
    s[threadIdx.x] = v;
    __syncthreads();
    for (int d = 1; d < 256; d <<= 1) {
        int t = (threadIdx.x >= d) ? s[threadIdx.x - d] : 0;
        __syncthreads();
        s[threadIdx.x] += t;
        __syncthreads();
    }
    if (i < N_NODES) offs[i] = s[threadIdx.x] - v;   // exclusive
    if (threadIdx.x == 255) bsum[blockIdx.x] = s[255];
}

__global__ void k_scan2(int* __restrict__ bsum, int nb) {
    __shared__ int s[256];
    int v = (threadIdx.x < nb) ? bsum[threadIdx.x] : 0;
    s[threadIdx.x] = v;
    __syncthreads();
    for (int d = 1; d < 256; d <<= 1) {
        int t = (threadIdx.x >= d) ? s[threadIdx.x - d] : 0;
        __syncthreads();
        s[threadIdx.x] += t;
        __syncthreads();
    }
    if (threadIdx.x < nb) bsum[threadIdx.x] = s[threadIdx.x] - v;  // exclusive
}

__global__ void k_scan3(int* __restrict__ offs, const int* __restrict__ bsum) {
    int i = blockIdx.x * 256 + threadIdx.x;
    if (i < N_NODES) offs[i] += bsum[blockIdx.x];
}

__global__ void k_scatter(const int* __restrict__ ei, const int* __restrict__ offs,
                          int* __restrict__ cursor, int* __restrict__ srcs) {
    int e = blockIdx.x * 256 + threadIdx.x;
    if (e >= E_TOT) return;
    int src, dst;
    if (e < E_RAW) { src = ei[e]; dst = ei[E_RAW + e]; }
    else           { src = dst = e - E_RAW; }
    int pos = offs[dst] + atomicAdd(&cursor[dst], 1);
    srcs[pos] = src;
}

// ---------------- W splits: all three layers in one launch ----------------
// W0,W1: [256][256] -> [n][k] bf16 hi/lo.  W2: [256][32] -> [32][256] hi/lo.

__global__ void k_split_all(const float* __restrict__ W0, const float* __restrict__ W1,
                            const float* __restrict__ W2,
                            bf16_t* __restrict__ T0h, bf16_t* __restrict__ T0l,
                            bf16_t* __restrict__ T1h, bf16_t* __restrict__ T1l,
                            bf16_t* __restrict__ T2h, bf16_t* __restrict__ T2l) {
    int idx = blockIdx.x * 256 + threadIdx.x;    // 139264 total
    float v; bf16_t *ph, *pl; int o;
    if (idx < 65536) {
        int k = idx >> 8, n = idx & 255;
        v = W0[idx]; ph = T0h; pl = T0l; o = n * 256 + k;
    } else if (idx < 131072) {
        int i = idx - 65536;
        int k = i >> 8, n = i & 255;
        v = W1[i]; ph = T1h; pl = T1l; o = n * 256 + k;
    } else {
        int i = idx - 131072;                    // < 8192
        int k = i >> 5, n = i & 31;
        v = W2[i]; ph = T2h; pl = T2l; o = n * 256 + k;
    }
    bf16_t h = (bf16_t)v;
    ph[o] = h;
    pl[o] = (bf16_t)(v - (float)h);
}

// ---------------- MFMA GEMM: TLP-first, small wave tile, plain loads --------
// Block 256 thr = 4 waves; BM=32 rows/block, BN=256; wave wv owns cols
// wv*64..+63 as 2x4 16x16 fragments over the block's 32 rows. Global layout
// [row][k]/[col][k] matches the MFMA fragment layout (lane l: row/col l&15,
// k-elems (l>>4)*8..+7) -> direct b128 loads. No LDS staging, no dbuf: grid
// is 1564 blocks (~6/CU, ~24 waves/CU) and wave-level TLP hides load latency
// (m114). Small register state (~100 VGPR) keeps occupancy high.
// Alpha dots reduced across the 4 waves via tiny LDS; plain stores.

template<bool A_FP32>
__global__ __launch_bounds__(256) void k_gemm256_mfma(
        const float* __restrict__ Af, const bf16_t* __restrict__ Ab,
        const bf16_t* __restrict__ Bth, const bf16_t* __restrict__ Btl,
        const float* __restrict__ a_s, const float* __restrict__ a_d,
        bf16_t* __restrict__ Hb, float* __restrict__ As, float* __restrict__ Ad) {
    const int tid  = threadIdx.x;
    const int lane = tid & 63;
    const int wv   = tid >> 6;
    const int r16  = lane & 15;
    const int kg   = lane >> 4;
    const int rowg = blockIdx.x * 32;
    const int colw = wv * 64;

    int aoff[2], boff[4];
    #pragma unroll
    for (int m = 0; m < 2; ++m) {
        int row = rowg + m * 16 + r16;
        if (A_FP32 && row >= N_NODES) row = N_NODES - 1;  // fp32 src unpadded
        aoff[m] = row * 256 + kg * 8;
    }
    #pragma unroll
    for (int n = 0; n < 4; ++n)
        boff[n] = (colw + n * 16 + r16) * 256 + kg * 8;

    f32x4 acc[2][4] = {};

    #pragma unroll
    for (int kk = 0; kk < 8; ++kk) {
        const int k0 = kk * 32;
        bf16x8 ah[2], al[2], bh[4], bl[4];
        #pragma unroll
        for (int n = 0; n < 4; ++n) {
            bh[n] = *(const bf16x8*)(Bth + boff[n] + k0);
            bl[n] = *(const bf16x8*)(Btl + boff[n] + k0);
        }
        if constexpr (A_FP32) {
            #pragma unroll
            for (int m = 0; m < 2; ++m) {
                float4 v0 = *(const float4*)(Af + aoff[m] + k0);
                float4 v1 = *(const float4*)(Af + aoff[m] + k0 + 4);
                float f[8] = {v0.x, v0.y, v0.z, v0.w, v1.x, v1.y, v1.z, v1.w};
                #pragma unroll
                for (int i = 0; i < 8; ++i) {
                    bf16_t h = (bf16_t)f[i];
                    ah[m][i] = h;
                    al[m][i] = (bf16_t)(f[i] - (float)h);
                }
            }
        } else {
            #pragma unroll
            for (int m = 0; m < 2; ++m)
                ah[m] = *(const bf16x8*)(Ab + aoff[m] + k0);
        }
        #pragma unroll
        for (int m = 0; m < 2; ++m) {
            #pragma unroll
            for (int n = 0; n < 4; ++n) {
                acc[m][n] = __builtin_amdgcn_mfma_f32_16x16x32_bf16(ah[m], bh[n], acc[m][n], 0, 0, 0);
                acc[m][n] = __builtin_amdgcn_mfma_f32_16x16x32_bf16(ah[m], bl[n], acc[m][n], 0, 0, 0);
                if constexpr (A_FP32)
                    acc[m][n] = __builtin_amdgcn_mfma_f32_16x16x32_bf16(al[m], bh[n], acc[m][n], 0, 0, 0);
            }
        }
    }

    // ---- epilogue: store bf16 H; alpha dots via shfl + cross-wave LDS reduce ----
    __shared__ float redS[4][32], redD[4][32];
    float asv[4], adv[4];
    #pragma unroll
    for (int n = 0; n < 4; ++n) {
        int col = colw + n * 16 + r16;
        asv[n] = a_s[col];
        adv[n] = a_d[col];
    }
    #pragma unroll
    for (int m = 0; m < 2; ++m) {
        #pragma unroll
        for (int j = 0; j < 4; ++j) {
            int rl  = m * 16 + kg * 4 + j;
            int row = rowg + rl;
            bool ok = row < N_NODES;
            float ss = 0.f, sd = 0.f;
            #pragma unroll
            for (int n = 0; n < 4; ++n) {
                float v = acc[m][n][j];
                if (ok) Hb[row * 256 + colw + n * 16 + r16] = (bf16_t)v;
                ss += v * asv[n];
                sd += v * adv[n];
            }
            #pragma unroll
            for (int o = 1; o < 16; o <<= 1) {
                ss += __shfl_xor(ss, o);
                sd += __shfl_xor(sd, o);
            }
            if (r16 == 0) { redS[wv][rl] = ss; redD[wv][rl] = sd; }
        }
    }
    __syncthreads();
    if (tid < 32) {
        int row = rowg + tid;
        if (row < N_NODES) {
            float s = redS[0][tid] + redS[1][tid] + redS[2][tid] + redS[3][tid];
            float d = redD[0][tid] + redD[1][tid] + redD[2][tid] + redD[3][tid];
            As[row] = s;
            Ad[row] = d;
        }
    }
}

// ---------------- GEMM 32-out (layer 2), MFMA, same TLP-first style ---------
// Block 256 thr = 4 waves; each wave 64 rows x all 32 cols (2 n-frags).

__global__ __launch_bounds__(256) void k_gemm32_mfma(
        const bf16_t* __restrict__ Ab,                          // [PAD_ROWS][256]
        const bf16_t* __restrict__ Bth, const bf16_t* __restrict__ Btl,  // [32][256]
        const float* __restrict__ a_s, const float* __restrict__ a_d,
        float* __restrict__ Hc, float* __restrict__ As, float* __restrict__ Ad) {
    const int tid  = threadIdx.x;
    const int lane = tid & 63;
    const int wv   = tid >> 6;
    const int r16  = lane & 15;
    const int kg   = lane >> 4;
    const int rowg = blockIdx.x * 256 + wv * 64;

    int aoff[4], boff[2];
    #pragma unroll
    for (int m = 0; m < 4; ++m) {
        int row = rowg + m * 16 + r16;
        if (row >= N_NODES) row = N_NODES - 1;   // grid overshoots PAD_ROWS
        aoff[m] = row * 256 + kg * 8;
    }
    #pragma unroll
    for (int n = 0; n < 2; ++n)
        boff[n] = (n * 16 + r16) * 256 + kg * 8;

    f32x4 acc[4][2] = {};

    #pragma unroll
    for (int kk = 0; kk < 8; ++kk) {
        const int k0 = kk * 32;
        bf16x8 ah[4], bh[2], bl[2];
        #pragma unroll
        for (int m = 0; m < 4; ++m)
            ah[m] = *(const bf16x8*)(Ab + aoff[m] + k0);
        #pragma unroll
        for (int n = 0; n < 2; ++n) {
            bh[n] = *(const bf16x8*)(Bth + boff[n] + k0);
            bl[n] = *(const bf16x8*)(Btl + boff[n] + k0);
        }
        #pragma unroll
        for (int m = 0; m < 4; ++m) {
            #pragma unroll
            for (int n = 0; n < 2; ++n) {
                acc[m][n] = __builtin_amdgcn_mfma_f32_16x16x32_bf16(ah[m], bh[n], acc[m][n], 0, 0, 0);
                acc[m][n] = __builtin_amdgcn_mfma_f32_16x16x32_bf16(ah[m], bl[n], acc[m][n], 0, 0, 0);
            }
        }
    }

    float asv[2], adv[2];
    #pragma unroll
    for (int n = 0; n < 2; ++n) {
        int col = n * 16 + r16;
        asv[n] = a_s[col];
        adv[n] = a_d[col];
    }
    #pragma unroll
    for (int m = 0; m < 4; ++m) {
        #pragma unroll
        for (int j = 0; j < 4; ++j) {
            int row = rowg + m * 16 + kg * 4 + j;
            bool ok = row < N_NODES;
            float ss = 0.f, sd = 0.f;
            #pragma unroll
            for (int n = 0; n < 2; ++n) {
                float v = acc[m][n][j];
                if (ok) Hc[row * 32 + n * 16 + r16] = v;
                ss += v * asv[n];
                sd += v * adv[n];
            }
            #pragma unroll
            for (int o = 1; o < 16; o <<= 1) {
                ss += __shfl_xor(ss, o);
                sd += __shfl_xor(sd, o);
            }
            if (ok && r16 == 0) { As[row] = ss; Ad[row] = sd; }
        }
    }
}

// ---------------- Attention: per-edge exp weights + per-node 1/denom ----------------

__global__ __launch_bounds__(256) void k_attn(
        const float* __restrict__ As, const float* __restrict__ Ad,
        const int* __restrict__ offs, const int* __restrict__ cnts,
        const int* __restrict__ srcs,
        int2* __restrict__ meta, float* __restrict__ inv) {
    const int lane = threadIdx.x & 63;
    int node = blockIdx.x * 4 + (threadIdx.x >> 6);
    if (node >= N_NODES) return;
    node = __builtin_amdgcn_readfirstlane(node);
    const int start = offs[node];
    const int cnt   = cnts[node];
    const float ad  = Ad[node];

    float m = -1e30f;
    for (int base = 0; base < cnt; base += 64) {
        int i = base + lane;
        if (i < cnt) {
            float e = As[srcs[start + i]] + ad;
            e = e > 0.f ? e : NEG_SLOPE * e;
            m = fmaxf(m, e);
        }
    }
    #pragma unroll
    for (int o = 32; o; o >>= 1) m = fmaxf(m, __shfl_xor(m, o));

    float denom = 0.f;
    for (int base = 0; base < cnt; base += 64) {
        int i = base + lane;
        if (i < cnt) {
            int s = srcs[start + i];
            float e = As[s] + ad;
            e = e > 0.f ? e : NEG_SLOPE * e;
            float p = __expf(e - m);
            denom += p;
            meta[start + i] = make_int2(s, __float_as_int(p));
        }
    }
    #pragma unroll
    for (int o = 32; o; o >>= 1) denom += __shfl_xor(denom, o);
    if (lane == 0) inv[node] = 1.f / denom;
}

// ---------------- Gather (256-wide bf16), fused bias + swish ----------------

__global__ __launch_bounds__(256) void k_gather256(
        const bf16_t* __restrict__ Hb, const int2* __restrict__ meta,
        const int* __restrict__ offs, const int* __restrict__ cnts,
        const float* __restrict__ inv,
        const float* __restrict__ bias, bf16_t* __restrict__ Hout) {
    const int lane = threadIdx.x & 63;
    int node = blockIdx.x * 4 + (threadIdx.x >> 6);
    if (node >= N_NODES) return;
    node = __builtin_amdgcn_readfirstlane(node);
    const int start = offs[node];
    const int cnt   = cnts[node];
    const float iv  = inv[node];
    const int c0 = lane * 4;

    float4 acc = {0.f, 0.f, 0.f, 0.f};
    for (int j = 0; j < cnt; j += 4) {
        int2 mp[4];
        #pragma unroll
        for (int k = 0; k < 4; ++k) mp[k] = meta[start + j + k];  // pad-safe
        #pragma unroll
        for (int k = 0; k < 4; ++k) {
            float p = (j + k < cnt) ? __int_as_float(mp[k].y) : 0.f;
            bf16x4 hv = *(const bf16x4*)&Hb[mp[k].x * 256 + c0];
            acc.x += p * (float)hv[0];
            acc.y += p * (float)hv[1];
            acc.z += p * (float)hv[2];
            acc.w += p * (float)hv[3];
        }
    }

    const float4 bv = *(const float4*)&bias[c0];
    float4 o4;
    o4.x = acc.x * iv + bv.x;
    o4.y = acc.y * iv + bv.y;
    o4.z = acc.z * iv + bv.z;
    o4.w = acc.w * iv + bv.w;
    o4.x = o4.x / (1.f + __expf(-o4.x));
    o4.y = o4.y / (1.f + __expf(-o4.y));
    o4.z = o4.z / (1.f + __expf(-o4.z));
    o4.w = o4.w / (1.f + __expf(-o4.w));
    bf16x4 st = {(bf16_t)o4.x, (bf16_t)o4.y, (bf16_t)o4.z, (bf16_t)o4.w};
    *(bf16x4*)&Hout[node * 256 + c0] = st;
}

// ---------------- Final gather (32-wide fp32) + bias + log_softmax ----------------

__global__ __launch_bounds__(256) void k_gather_final(
        const float* __restrict__ Hc,   // [N][32]
        const int2* __restrict__ meta,
        const int* __restrict__ offs, const int* __restrict__ cnts,
        const float* __restrict__ inv,
        const float* __restrict__ bias, float* __restrict__ out) {
    const int lane = threadIdx.x & 63;
    int node = blockIdx.x * 4 + (threadIdx.x >> 6);
    if (node >= N_NODES) return;
    node = __builtin_amdgcn_readfirstlane(node);
    const int start = offs[node];
    const int cnt   = cnts[node];
    const float iv  = inv[node];
    const int c = lane & 31;

    float acc = 0.f;
    for (int j = 0; j < cnt; j += 4) {
        int2 mp[4];
        #pragma unroll
        for (int k = 0; k < 4; ++k) mp[k] = meta[start + j + k];
        #pragma unroll
        for (int k = 0; k < 4; ++k) {
            float p = (j + k < cnt) ? __int_as_float(mp[k].y) : 0.f;
            acc += p * Hc[mp[k].x * 32 + c];
        }
    }

    float v = acc * iv + bias[c];
    float mm = v;
    #pragma unroll
    for (int o = 16; o; o >>= 1) mm = fmaxf(mm, __shfl_xor(mm, o));
    float ex = __expf(v - mm), sum = ex;
    #pragma unroll
    for (int o = 16; o; o >>= 1) sum += __shfl_xor(sum, o);
    float r = v - mm - __logf(sum);
    if (lane < 32) out[node * 32 + c] = r;
}

// ---------------- launch ----------------

extern "C" void kernel_launch(void* const* d_in, const int* in_sizes, int n_in,
                              void* d_out, int out_size, void* d_ws, size_t ws_size,
                              hipStream_t stream) {
    const float* x   = (const float*)d_in[0];
    const int*   ei  = (const int*)  d_in[1];
    const float* W0  = (const float*)d_in[2];
    const float* as0 = (const float*)d_in[3];
    const float* ad0 = (const float*)d_in[4];
    const float* b0  = (const float*)d_in[5];
    const float* W1  = (const float*)d_in[6];
    const float* as1 = (const float*)d_in[7];
    const float* ad1 = (const float*)d_in[8];
    const float* b1  = (const float*)d_in[9];
    const float* W2  = (const float*)d_in[10];
    const float* as2 = (const float*)d_in[11];
    const float* ad2 = (const float*)d_in[12];
    const float* b2  = (const float*)d_in[13];
    float* out = (float*)d_out;

    char* ws = (char*)d_ws;
    // padded bf16 feature buffers: PAD_ROWS*256*2 = 25,624,576 B each
    bf16_t* hA_b  = (bf16_t*)(ws + 0);
    bf16_t* hB_b  = (bf16_t*)(ws + 25624576);
    float*  hC    = (float*) (ws + 51249152);   //  6,400,000
    float*  As    = (float*) (ws + 57649152);
    float*  Ad    = (float*) (ws + 57849152);
    float*  inv   = (float*) (ws + 58049152);
    int*    cnts  = (int*)   (ws + 58249152);
    int*    offs  = (int*)   (ws + 58449152);
    int*    cursor= (int*)   (ws + 58649152);
    int*    srcs  = (int*)   (ws + 58849152);   //  1,800,000
    int2*   meta  = (int2*)  (ws + 60649152);   //  3,600,032 (E_TOT+4)
    int*    bsum  = (int*)   (ws + 64249184);   //      1,024
    bf16_t* Wth0  = (bf16_t*)(ws + 64250208);   //    131,072
    bf16_t* Wtl0  = (bf16_t*)(ws + 64381280);   //    131,072
    bf16_t* Wth1  = (bf16_t*)(ws + 64512352);   //    131,072
    bf16_t* Wtl1  = (bf16_t*)(ws + 64643424);   //    131,072
    bf16_t* Wth2  = (bf16_t*)(ws + 64774496);   //     16,384
    bf16_t* Wtl2  = (bf16_t*)(ws + 64790880);   //     16,384 -> end 64,807,264

    const int NB = (N_NODES + 255) / 256;       // 196

    hipMemsetAsync(cnts,   0, N_NODES * sizeof(int), stream);
    hipMemsetAsync(cursor, 0, N_NODES * sizeof(int), stream);
    hipMemsetAsync((char*)meta + (size_t)E_TOT * 8, 0, 32, stream);  // pad

    k_hist     <<<(E_TOT + 255) / 256, 256, 0, stream>>>(ei, cnts);
    k_scan1    <<<NB, 256, 0, stream>>>(cnts, offs, bsum);
    k_scan2    <<<1, 256, 0, stream>>>(bsum, NB);
    k_scan3    <<<NB, 256, 0, stream>>>(offs, bsum);
    k_scatter  <<<(E_TOT + 255) / 256, 256, 0, stream>>>(ei, offs, cursor, srcs);
    k_split_all<<<544, 256, 0, stream>>>(W0, W1, W2, Wth0, Wtl0, Wth1, Wtl1, Wth2, Wtl2);

    const int AGG_BLOCKS  = (N_NODES + 3) / 4;   // 12500
    const int GEMM_BLOCKS = PAD_ROWS / 32;       // 1564

    // layer 0 (A = x fp32, in-register hi/lo split)
    k_gemm256_mfma<true><<<GEMM_BLOCKS, 256, 0, stream>>>(x, nullptr, Wth0, Wtl0, as0, ad0, hA_b, As, Ad);
    k_attn<<<AGG_BLOCKS, 256, 0, stream>>>(As, Ad, offs, cnts, srcs, meta, inv);
    k_gather256<<<AGG_BLOCKS, 256, 0, stream>>>(hA_b, meta, offs, cnts, inv, b0, hB_b);
    // layer 1 (A exact bf16)
    k_gemm256_mfma<false><<<GEMM_BLOCKS, 256, 0, stream>>>(nullptr, hB_b, Wth1, Wtl1, as1, ad1, hA_b, As, Ad);
    k_attn<<<AGG_BLOCKS, 256, 0, stream>>>(As, Ad, offs, cnts, srcs, meta, inv);
    k_gather256<<<AGG_BLOCKS, 256, 0, stream>>>(hA_b, meta, offs, cnts, inv, b1, hB_b);
    // layer 2 (+ fused log_softmax)
    k_gemm32_mfma<<<NB, 256, 0, stream>>>(hB_b, Wth2, Wtl2, as2, ad2, hC, As, Ad);
    k_attn<<<AGG_BLOCKS, 256, 0, stream>>>(As, Ad, offs, cnts, srcs, meta, inv);
    k_gather_final<<<AGG_BLOCKS, 256, 0, stream>>>(hC, meta, offs, cnts, inv, b2, out);
}

// Round 9
// 295.360 us; speedup vs baseline: 1.2429x; 1.2429x over previous
//
#include <hip/hip_runtime.h>
#include <math.h>

#define N_NODES 50000
#define PAD_ROWS 50048                 // 782 * 64
#define N_TILES  782                   // 64-row tiles
#define GEMM_BLOCKS_P 256              // persistent: 1 block/CU
#define E_RAW   400000
#define E_TOT   (E_RAW + N_NODES)      // 450000 incl. self loops
#define NEG_SLOPE 0.2f

typedef __bf16 bf16_t;
typedef bf16_t bf16x8 __attribute__((ext_vector_type(8)));
typedef bf16_t bf16x4 __attribute__((ext_vector_type(4)));
typedef float  f32x4  __attribute__((ext_vector_type(4)));

__device__ __forceinline__ void gll16(const void* g, void* l) {
    __builtin_amdgcn_global_load_lds(
        (const __attribute__((address_space(1))) void*)g,
        (__attribute__((address_space(3))) void*)l, 16, 0, 0);
}

// ---------------- CSR build ----------------

__global__ void k_hist(const int* __restrict__ ei, int* __restrict__ cnt) {
    int e = blockIdx.x * 256 + threadIdx.x;
    if (e >= E_TOT) return;
    int dst = (e < E_RAW) ? ei[E_RAW + e] : (e - E_RAW);
    atomicAdd(&cnt[dst], 1);
}

__global__ void k_scan1(const int* __restrict__ cnt, int* __restrict__ offs,
                        int* __restrict__ bsum) {
    __shared__ int s[256];
    int i = blockIdx.x * 256 + threadIdx.x;
    int v = (i < N_NODES) ? cnt[i] : 0;
    s[threadIdx.x] = v;
    __syncthreads();
    for (int d = 1; d < 256; d <<= 1) {
        int t = (threadIdx.x >= d) ? s[threadIdx.x - d] : 0;
        __syncthreads();
        s[threadIdx.x] += t;
        __syncthreads();
    }
    if (i < N_NODES) offs[i] = s[threadIdx.x] - v;   // exclusive
    if (threadIdx.x == 255) bsum[blockIdx.x] = s[255];
}

__global__ void k_scan2(int* __restrict__ bsum, int nb) {
    __shared__ int s[256];
    int v = (threadIdx.x < nb) ? bsum[threadIdx.x] : 0;
    s[threadIdx.x] = v;
    __syncthreads();
    for (int d = 1; d < 256; d <<= 1) {
        int t = (threadIdx.x >= d) ? s[threadIdx.x - d] : 0;
        __syncthreads();
        s[threadIdx.x] += t;
        __syncthreads();
    }
    if (threadIdx.x < nb) bsum[threadIdx.x] = s[threadIdx.x] - v;  // exclusive
}

__global__ void k_scan3(int* __restrict__ offs, const int* __restrict__ bsum) {
    int i = blockIdx.x * 256 + threadIdx.x;
    if (i < N_NODES) offs[i] += bsum[blockIdx.x];
}

__global__ void k_scatter(const int* __restrict__ ei, const int* __restrict__ offs,
                          int* __restrict__ cursor, int* __restrict__ srcs) {
    int e = blockIdx.x * 256 + threadIdx.x;
    if (e >= E_TOT) return;
    int src, dst;
    if (e < E_RAW) { src = ei[e]; dst = ei[E_RAW + e]; }
    else           { src = dst = e - E_RAW; }
    int pos = offs[dst] + atomicAdd(&cursor[dst], 1);
    srcs[pos] = src;
}

// ---------------- W splits: all three layers in one launch ----------------
// W0,W1: [256][256] -> [n][k] bf16 hi/lo.  W2: [256][32] -> [32][256] hi/lo.
// (lo of W0/W1 unused by the persistent GEMM - hi-only LDS residency.)

__global__ void k_split_all(const float* __restrict__ W0, const float* __restrict__ W1,
                            const float* __restrict__ W2,
                            bf16_t* __restrict__ T0h, bf16_t* __restrict__ T0l,
                            bf16_t* __restrict__ T1h, bf16_t* __restrict__ T1l,
                            bf16_t* __restrict__ T2h, bf16_t* __restrict__ T2l) {
    int idx = blockIdx.x * 256 + threadIdx.x;    // 139264 total
    float v; bf16_t *ph, *pl; int o;
    if (idx < 65536) {
        int k = idx >> 8, n = idx & 255;
        v = W0[idx]; ph = T0h; pl = T0l; o = n * 256 + k;
    } else if (idx < 131072) {
        int i = idx - 65536;
        int k = i >> 8, n = i & 255;
        v = W1[i]; ph = T1h; pl = T1l; o = n * 256 + k;
    } else {
        int i = idx - 131072;                    // < 8192
        int k = i >> 5, n = i & 31;
        v = W2[i]; ph = T2h; pl = T2l; o = n * 256 + k;
    }
    bf16_t h = (bf16_t)v;
    ph[o] = h;
    pl[o] = (bf16_t)(v - (float)h);
}

// ---------------- Persistent MFMA GEMM: whole B-hi resident in LDS ---------
// Grid = 256 blocks (1/CU) x 512 thr (8 waves). Stage B-hi (256x256 bf16 =
// 128KB) into LDS ONCE, frag-major ([n_sub][kk][lane*8], ds_read_b128
// conflict-free), then grid-stride over 64-row M-tiles. Wave (wr,wc) of 2x4
// owns 32 rows x 64 cols = 2x4 16x16 fragments. A fragments load direct
// global->VGPR (row-major-in-k matches MFMA layout: lane l -> row l&15,
// k-elems (l>>4)*8..+7). B re-read from L2 is eliminated (was ~200MB/launch,
// the measured ~4TB/s L2-return bottleneck of R4-R8).
// A_FP32: x split hi/lo in-register -> 2 MFMA/frag; else exact bf16 -> 1.

template<bool A_FP32>
__global__ __launch_bounds__(512) void k_gemm256_persist(
        const float* __restrict__ Af, const bf16_t* __restrict__ Ab,
        const bf16_t* __restrict__ Bth,
        const float* __restrict__ a_s, const float* __restrict__ a_d,
        bf16_t* __restrict__ Hb, float* __restrict__ As, float* __restrict__ Ad) {
    __shared__ __align__(16) bf16_t Bs[16][8][512];   // 131072 B
    __shared__ float redS[4][64], redD[4][64];        //   2048 B

    const int tid  = threadIdx.x;
    const int lane = tid & 63;
    const int w    = tid >> 6;       // 0..7
    const int wr   = w >> 2;         // 0..1: row half (32 rows)
    const int wc   = w & 3;          // 0..3: col quarter (64 cols)
    const int r16  = lane & 15;
    const int kg   = lane >> 4;      // 0..3

    // ---- stage whole B-hi once: 128 wave-ops of 1KB, 16 per wave ----
    #pragma unroll
    for (int i = 0; i < 16; ++i) {
        int op   = w * 16 + i;       // 0..127
        int nsub = op >> 3;          // 0..15
        int kk   = op & 7;           // 0..7
        gll16(&Bth[(nsub * 16 + r16) * 256 + kk * 32 + kg * 8], &Bs[nsub][kk][0]);
    }

    float asv[4], adv[4];
    #pragma unroll
    for (int n = 0; n < 4; ++n) {
        int col = wc * 64 + n * 16 + r16;
        asv[n] = a_s[col];
        adv[n] = a_d[col];
    }
    __syncthreads();   // drains staging vmcnt; B resident for whole kernel

    for (int tile = blockIdx.x; tile < N_TILES; tile += GEMM_BLOCKS_P) {
        const int rowg = tile * 64 + wr * 32;
        int aoff[2];
        #pragma unroll
        for (int m = 0; m < 2; ++m) {
            int row = rowg + m * 16 + r16;
            if (A_FP32 && row >= N_NODES) row = N_NODES - 1;  // fp32 src unpadded
            aoff[m] = row * 256 + kg * 8;
        }

        f32x4 acc[2][4] = {};
        #pragma unroll
        for (int kk = 0; kk < 8; ++kk) {
            const int k0 = kk * 32;
            bf16x8 ah[2], al[2], bf[4];
            #pragma unroll
            for (int n = 0; n < 4; ++n)
                bf[n] = *(const bf16x8*)&Bs[wc * 4 + n][kk][lane * 8];
            if constexpr (A_FP32) {
                #pragma unroll
                for (int m = 0; m < 2; ++m) {
                    float4 v0 = *(const float4*)(Af + aoff[m] + k0);
                    float4 v1 = *(const float4*)(Af + aoff[m] + k0 + 4);
                    float f[8] = {v0.x, v0.y, v0.z, v0.w, v1.x, v1.y, v1.z, v1.w};
                    #pragma unroll
                    for (int i = 0; i < 8; ++i) {
                        bf16_t h = (bf16_t)f[i];
                        ah[m][i] = h;
                        al[m][i] = (bf16_t)(f[i] - (float)h);
                    }
                }
            } else {
                #pragma unroll
                for (int m = 0; m < 2; ++m)
                    ah[m] = *(const bf16x8*)(Ab + aoff[m] + k0);
            }
            #pragma unroll
            for (int m = 0; m < 2; ++m) {
                #pragma unroll
                for (int n = 0; n < 4; ++n) {
                    acc[m][n] = __builtin_amdgcn_mfma_f32_16x16x32_bf16(ah[m], bf[n], acc[m][n], 0, 0, 0);
                    if constexpr (A_FP32)
                        acc[m][n] = __builtin_amdgcn_mfma_f32_16x16x32_bf16(al[m], bf[n], acc[m][n], 0, 0, 0);
                }
            }
        }

        // ---- epilogue: store bf16 H; alpha dots shfl + cross-wave LDS reduce ----
        #pragma unroll
        for (int m = 0; m < 2; ++m) {
            #pragma unroll
            for (int j = 0; j < 4; ++j) {
                int rl  = m * 16 + kg * 4 + j;       // 0..31 in wave's rows
                int row = rowg + rl;
                bool ok = row < N_NODES;
                float ss = 0.f, sd = 0.f;
                #pragma unroll
                for (int n = 0; n < 4; ++n) {
                    float v = acc[m][n][j];
                    if (ok) Hb[row * 256 + wc * 64 + n * 16 + r16] = (bf16_t)v;
                    ss += v * asv[n];
                    sd += v * adv[n];
                }
                #pragma unroll
                for (int o = 1; o < 16; o <<= 1) {
                    ss += __shfl_xor(ss, o);
                    sd += __shfl_xor(sd, o);
                }
                if (r16 == 0) {
                    redS[wc][wr * 32 + rl] = ss;
                    redD[wc][wr * 32 + rl] = sd;
                }
            }
        }
        __syncthreads();
        if (tid < 64) {
            int row = tile * 64 + tid;
            if (row < N_NODES) {
                As[row] = redS[0][tid] + redS[1][tid] + redS[2][tid] + redS[3][tid];
                Ad[row] = redD[0][tid] + redD[1][tid] + redD[2][tid] + redD[3][tid];
            }
        }
        __syncthreads();
    }
}

// ---------------- GEMM 32-out (layer 2), MFMA (W2 keeps hi+lo) -------------
// Block 256 thr = 4 waves; each wave 64 rows x all 32 cols (2 n-frags).

__global__ __launch_bounds__(256) void k_gemm32_mfma(
        const bf16_t* __restrict__ Ab,                          // [PAD_ROWS][256]
        const bf16_t* __restrict__ Bth, const bf16_t* __restrict__ Btl,  // [32][256]
        const float* __restrict__ a_s, const float* __restrict__ a_d,
        float* __restrict__ Hc, float* __restrict__ As, float* __restrict__ Ad) {
    const int tid  = threadIdx.x;
    const int lane = tid & 63;
    const int wv   = tid >> 6;
    const int r16  = lane & 15;
    const int kg   = lane >> 4;
    const int rowg = blockIdx.x * 256 + wv * 64;

    int aoff[4], boff[2];
    #pragma unroll
    for (int m = 0; m < 4; ++m) {
        int row = rowg + m * 16 + r16;
        if (row >= N_NODES) row = N_NODES - 1;   // grid overshoots PAD_ROWS
        aoff[m] = row * 256 + kg * 8;
    }
    #pragma unroll
    for (int n = 0; n < 2; ++n)
        boff[n] = (n * 16 + r16) * 256 + kg * 8;

    f32x4 acc[4][2] = {};

    #pragma unroll
    for (int kk = 0; kk < 8; ++kk) {
        const int k0 = kk * 32;
        bf16x8 ah[4], bh[2], bl[2];
        #pragma unroll
        for (int m = 0; m < 4; ++m)
            ah[m] = *(const bf16x8*)(Ab + aoff[m] + k0);
        #pragma unroll
        for (int n = 0; n < 2; ++n) {
            bh[n] = *(const bf16x8*)(Bth + boff[n] + k0);
            bl[n] = *(const bf16x8*)(Btl + boff[n] + k0);
        }
        #pragma unroll
        for (int m = 0; m < 4; ++m) {
            #pragma unroll
            for (int n = 0; n < 2; ++n) {
                acc[m][n] = __builtin_amdgcn_mfma_f32_16x16x32_bf16(ah[m], bh[n], acc[m][n], 0, 0, 0);
                acc[m][n] = __builtin_amdgcn_mfma_f32_16x16x32_bf16(ah[m], bl[n], acc[m][n], 0, 0, 0);
            }
        }
    }

    float asv[2], adv[2];
    #pragma unroll
    for (int n = 0; n < 2; ++n) {
        int col = n * 16 + r16;
        asv[n] = a_s[col];
        adv[n] = a_d[col];
    }
    #pragma unroll
    for (int m = 0; m < 4; ++m) {
        #pragma unroll
        for (int j = 0; j < 4; ++j) {
            int row = rowg + m * 16 + kg * 4 + j;
            bool ok = row < N_NODES;
            float ss = 0.f, sd = 0.f;
            #pragma unroll
            for (int n = 0; n < 2; ++n) {
                float v = acc[m][n][j];
                if (ok) Hc[row * 32 + n * 16 + r16] = v;
                ss += v * asv[n];
                sd += v * adv[n];
            }
            #pragma unroll
            for (int o = 1; o < 16; o <<= 1) {
                ss += __shfl_xor(ss, o);
                sd += __shfl_xor(sd, o);
            }
            if (ok && r16 == 0) { As[row] = ss; Ad[row] = sd; }
        }
    }
}

// ---------------- Attention: per-edge exp weights + per-node 1/denom ----------------

__global__ __launch_bounds__(256) void k_attn(
        const float* __restrict__ As, const float* __restrict__ Ad,
        const int* __restrict__ offs, const int* __restrict__ cnts,
        const int* __restrict__ srcs,
        int2* __restrict__ meta, float* __restrict__ inv) {
    const int lane = threadIdx.x & 63;
    int node = blockIdx.x * 4 + (threadIdx.x >> 6);
    if (node >= N_NODES) return;
    node = __builtin_amdgcn_readfirstlane(node);
    const int start = offs[node];
    const int cnt   = cnts[node];
    const float ad  = Ad[node];

    float m = -1e30f;
    for (int base = 0; base < cnt; base += 64) {
        int i = base + lane;
        if (i < cnt) {
            float e = As[srcs[start + i]] + ad;
            e = e > 0.f ? e : NEG_SLOPE * e;
            m = fmaxf(m, e);
        }
    }
    #pragma unroll
    for (int o = 32; o; o >>= 1) m = fmaxf(m, __shfl_xor(m, o));

    float denom = 0.f;
    for (int base = 0; base < cnt; base += 64) {
        int i = base + lane;
        if (i < cnt) {
            int s = srcs[start + i];
            float e = As[s] + ad;
            e = e > 0.f ? e : NEG_SLOPE * e;
            float p = __expf(e - m);
            denom += p;
            meta[start + i] = make_int2(s, __float_as_int(p));
        }
    }
    #pragma unroll
    for (int o = 32; o; o >>= 1) denom += __shfl_xor(denom, o);
    if (lane == 0) inv[node] = 1.f / denom;
}

// ---------------- Gather (256-wide bf16), fused bias + swish ----------------

__global__ __launch_bounds__(256) void k_gather256(
        const bf16_t* __restrict__ Hb, const int2* __restrict__ meta,
        const int* __restrict__ offs, const int* __restrict__ cnts,
        const float* __restrict__ inv,
        const float* __restrict__ bias, bf16_t* __restrict__ Hout) {
    const int lane = threadIdx.x & 63;
    int node = blockIdx.x * 4 + (threadIdx.x >> 6);
    if (node >= N_NODES) return;
    node = __builtin_amdgcn_readfirstlane(node);
    const int start = offs[node];
    const int cnt   = cnts[node];
    const float iv  = inv[node];
    const int c0 = lane * 4;

    float4 acc = {0.f, 0.f, 0.f, 0.f};
    for (int j = 0; j < cnt; j += 4) {
        int2 mp[4];
        #pragma unroll
        for (int k = 0; k < 4; ++k) mp[k] = meta[start + j + k];  // pad-safe
        #pragma unroll
        for (int k = 0; k < 4; ++k) {
            float p = (j + k < cnt) ? __int_as_float(mp[k].y) : 0.f;
            bf16x4 hv = *(const bf16x4*)&Hb[mp[k].x * 256 + c0];
            acc.x += p * (float)hv[0];
            acc.y += p * (float)hv[1];
            acc.z += p * (float)hv[2];
            acc.w += p * (float)hv[3];
        }
    }

    const float4 bv = *(const float4*)&bias[c0];
    float4 o4;
    o4.x = acc.x * iv + bv.x;
    o4.y = acc.y * iv + bv.y;
    o4.z = acc.z * iv + bv.z;
    o4.w = acc.w * iv + bv.w;
    o4.x = o4.x / (1.f + __expf(-o4.x));
    o4.y = o4.y / (1.f + __expf(-o4.y));
    o4.z = o4.z / (1.f + __expf(-o4.z));
    o4.w = o4.w / (1.f + __expf(-o4.w));
    bf16x4 st = {(bf16_t)o4.x, (bf16_t)o4.y, (bf16_t)o4.z, (bf16_t)o4.w};
    *(bf16x4*)&Hout[node * 256 + c0] = st;
}

// ---------------- Final gather (32-wide fp32) + bias + log_softmax ----------------

__global__ __launch_bounds__(256) void k_gather_final(
        const float* __restrict__ Hc,   // [N][32]
        const int2* __restrict__ meta,
        const int* __restrict__ offs, const int* __restrict__ cnts,
        const float* __restrict__ inv,
        const float* __restrict__ bias, float* __restrict__ out) {
    const int lane = threadIdx.x & 63;
    int node = blockIdx.x * 4 + (threadIdx.x >> 6);
    if (node >= N_NODES) return;
    node = __builtin_amdgcn_readfirstlane(node);
    const int start = offs[node];
    const int cnt   = cnts[node];
    const float iv  = inv[node];
    const int c = lane & 31;

    float acc = 0.f;
    for (int j = 0; j < cnt; j += 4) {
        int2 mp[4];
        #pragma unroll
        for (int k = 0; k < 4; ++k) mp[k] = meta[start + j + k];
        #pragma unroll
        for (int k = 0; k < 4; ++k) {
            float p = (j + k < cnt) ? __int_as_float(mp[k].y) : 0.f;
            acc += p * Hc[mp[k].x * 32 + c];
        }
    }

    float v = acc * iv + bias[c];
    float mm = v;
    #pragma unroll
    for (int o = 16; o; o >>= 1) mm = fmaxf(mm, __shfl_xor(mm, o));
    float ex = __expf(v - mm), sum = ex;
    #pragma unroll
    for (int o = 16; o; o >>= 1) sum += __shfl_xor(sum, o);
    float r = v - mm - __logf(sum);
    if (lane < 32) out[node * 32 + c] = r;
}

// ---------------- launch ----------------

extern "C" void kernel_launch(void* const* d_in, const int* in_sizes, int n_in,
                              void* d_out, int out_size, void* d_ws, size_t ws_size,
                              hipStream_t stream) {
    const float* x   = (const float*)d_in[0];
    const int*   ei  = (const int*)  d_in[1];
    const float* W0  = (const float*)d_in[2];
    const float* as0 = (const float*)d_in[3];
    const float* ad0 = (const float*)d_in[4];
    const float* b0  = (const float*)d_in[5];
    const float* W1  = (const float*)d_in[6];
    const float* as1 = (const float*)d_in[7];
    const float* ad1 = (const float*)d_in[8];
    const float* b1  = (const float*)d_in[9];
    const float* W2  = (const float*)d_in[10];
    const float* as2 = (const float*)d_in[11];
    const float* ad2 = (const float*)d_in[12];
    const float* b2  = (const float*)d_in[13];
    float* out = (float*)d_out;

    char* ws = (char*)d_ws;
    // padded bf16 feature buffers: PAD_ROWS*256*2 = 25,624,576 B each
    bf16_t* hA_b  = (bf16_t*)(ws + 0);
    bf16_t* hB_b  = (bf16_t*)(ws + 25624576);
    float*  hC    = (float*) (ws + 51249152);   //  6,400,000
    float*  As    = (float*) (ws + 57649152);
    float*  Ad    = (float*) (ws + 57849152);
    float*  inv   = (float*) (ws + 58049152);
    int*    cnts  = (int*)   (ws + 58249152);
    int*    offs  = (int*)   (ws + 58449152);
    int*    cursor= (int*)   (ws + 58649152);
    int*    srcs  = (int*)   (ws + 58849152);   //  1,800,000
    int2*   meta  = (int2*)  (ws + 60649152);   //  3,600,032 (E_TOT+4)
    int*    bsum  = (int*)   (ws + 64249184);   //      1,024
    bf16_t* Wth0  = (bf16_t*)(ws + 64250208);   //    131,072
    bf16_t* Wtl0  = (bf16_t*)(ws + 64381280);   //    131,072
    bf16_t* Wth1  = (bf16_t*)(ws + 64512352);   //    131,072
    bf16_t* Wtl1  = (bf16_t*)(ws + 64643424);   //    131,072
    bf16_t* Wth2  = (bf16_t*)(ws + 64774496);   //     16,384
    bf16_t* Wtl2  = (bf16_t*)(ws + 64790880);   //     16,384 -> end 64,807,264

    const int NB = (N_NODES + 255) / 256;       // 196

    hipMemsetAsync(cnts,   0, N_NODES * sizeof(int), stream);
    hipMemsetAsync(cursor, 0, N_NODES * sizeof(int), stream);
    hipMemsetAsync((char*)meta + (size_t)E_TOT * 8, 0, 32, stream);  // pad

    k_hist     <<<(E_TOT + 255) / 256, 256, 0, stream>>>(ei, cnts);
    k_scan1    <<<NB, 256, 0, stream>>>(cnts, offs, bsum);
    k_scan2    <<<1, 256, 0, stream>>>(bsum, NB);
    k_scan3    <<<NB, 256, 0, stream>>>(offs, bsum);
    k_scatter  <<<(E_TOT + 255) / 256, 256, 0, stream>>>(ei, offs, cursor, srcs);
    k_split_all<<<544, 256, 0, stream>>>(W0, W1, W2, Wth0, Wtl0, Wth1, Wtl1, Wth2, Wtl2);

    const int AGG_BLOCKS = (N_NODES + 3) / 4;   // 12500

    // layer 0 (A = x fp32, in-register hi/lo split; W0 hi-only, LDS-resident)
    k_gemm256_persist<true><<<GEMM_BLOCKS_P, 512, 0, stream>>>(x, nullptr, Wth0, as0, ad0, hA_b, As, Ad);
    k_attn<<<AGG_BLOCKS, 256, 0, stream>>>(As, Ad, offs, cnts, srcs, meta, inv);
    k_gather256<<<AGG_BLOCKS, 256, 0, stream>>>(hA_b, meta, offs, cnts, inv, b0, hB_b);
    // layer 1 (A exact bf16; W1 hi-only, LDS-resident)
    k_gemm256_persist<false><<<GEMM_BLOCKS_P, 512, 0, stream>>>(nullptr, hB_b, Wth1, as1, ad1, hA_b, As, Ad);
    k_attn<<<AGG_BLOCKS, 256, 0, stream>>>(As, Ad, offs, cnts, srcs, meta, inv);
    k_gather256<<<AGG_BLOCKS, 256, 0, stream>>>(hA_b, meta, offs, cnts, inv, b1, hB_b);
    // layer 2 (+ fused log_softmax; W2 keeps hi+lo)
    k_gemm32_mfma<<<NB, 256, 0, stream>>>(hB_b, Wth2, Wtl2, as2, ad2, hC, As, Ad);
    k_attn<<<AGG_BLOCKS, 256, 0, stream>>>(As, Ad, offs, cnts, srcs, meta, inv);
    k_gather_final<<<AGG_BLOCKS, 256, 0, stream>>>(hC, meta, offs, cnts, inv, b2, out);
}

// Round 10
// 286.293 us; speedup vs baseline: 1.2823x; 1.0317x over previous
//
#include <hip/hip_runtime.h>
#include <math.h>

#define N_NODES 50000
#define PAD_ROWS 50048                 // 391 * 128
#define N_TILES128 391                 // 128-row tiles
#define GEMM_BLOCKS_P 256              // persistent: 1 block/CU
#define E_RAW   400000
#define E_TOT   (E_RAW + N_NODES)      // 450000 incl. self loops
#define NEG_SLOPE 0.2f

typedef __bf16 bf16_t;
typedef bf16_t bf16x8 __attribute__((ext_vector_type(8)));
typedef bf16_t bf16x4 __attribute__((ext_vector_type(4)));
typedef float  f32x4  __attribute__((ext_vector_type(4)));

__device__ __forceinline__ void gll16(const void* g, void* l) {
    __builtin_amdgcn_global_load_lds(
        (const __attribute__((address_space(1))) void*)g,
        (__attribute__((address_space(3))) void*)l, 16, 0, 0);
}

// ---------------- CSR build ----------------

__global__ void k_hist(const int* __restrict__ ei, int* __restrict__ cnt) {
    int e = blockIdx.x * 256 + threadIdx.x;
    if (e >= E_TOT) return;
    int dst = (e < E_RAW) ? ei[E_RAW + e] : (e - E_RAW);
    atomicAdd(&cnt[dst], 1);
}

__global__ void k_scan1(const int* __restrict__ cnt, int* __restrict__ offs,
                        int* __restrict__ bsum) {
    __shared__ int s[256];
    int i = blockIdx.x * 256 + threadIdx.x;
    int v = (i < N_NODES) ? cnt[i] : 0;
    s[threadIdx.x] = v;
    __syncthreads();
    for (int d = 1; d < 256; d <<= 1) {
        int t = (threadIdx.x >= d) ? s[threadIdx.x - d] : 0;
        __syncthreads();
        s[threadIdx.x] += t;
        __syncthreads();
    }
    if (i < N_NODES) offs[i] = s[threadIdx.x] - v;   // exclusive
    if (threadIdx.x == 255) bsum[blockIdx.x] = s[255];
}

__global__ void k_scan2(int* __restrict__ bsum, int nb) {
    __shared__ int s[256];
    int v = (threadIdx.x < nb) ? bsum[threadIdx.x] : 0;
    s[threadIdx.x] = v;
    __syncthreads();
    for (int d = 1; d < 256; d <<= 1) {
        int t = (threadIdx.x >= d) ? s[threadIdx.x - d] : 0;
        __syncthreads();
        s[threadIdx.x] += t;
        __syncthreads();
    }
    if (threadIdx.x < nb) bsum[threadIdx.x] = s[threadIdx.x] - v;  // exclusive
}

__global__ void k_scan3(int* __restrict__ offs, const int* __restrict__ bsum) {
    int i = blockIdx.x * 256 + threadIdx.x;
    if (i < N_NODES) offs[i] += bsum[blockIdx.x];
}

__global__ void k_scatter(const int* __restrict__ ei, const int* __restrict__ offs,
                          int* __restrict__ cursor, int* __restrict__ srcs) {
    int e = blockIdx.x * 256 + threadIdx.x;
    if (e >= E_TOT) return;
    int src, dst;
    if (e < E_RAW) { src = ei[e]; dst = ei[E_RAW + e]; }
    else           { src = dst = e - E_RAW; }
    int pos = offs[dst] + atomicAdd(&cursor[dst], 1);
    srcs[pos] = src;
}

// ---------------- W splits: all three layers in one launch ----------------
// W0,W1: [256][256] -> [n][k] bf16 hi/lo.  W2: [256][32] -> [32][256] hi/lo.
// (lo of W0/W1 unused by the persistent GEMM - hi-only LDS residency.)

__global__ void k_split_all(const float* __restrict__ W0, const float* __restrict__ W1,
                            const float* __restrict__ W2,
                            bf16_t* __restrict__ T0h, bf16_t* __restrict__ T0l,
                            bf16_t* __restrict__ T1h, bf16_t* __restrict__ T1l,
                            bf16_t* __restrict__ T2h, bf16_t* __restrict__ T2l) {
    int idx = blockIdx.x * 256 + threadIdx.x;    // 139264 total
    float v; bf16_t *ph, *pl; int o;
    if (idx < 65536) {
        int k = idx >> 8, n = idx & 255;
        v = W0[idx]; ph = T0h; pl = T0l; o = n * 256 + k;
    } else if (idx < 131072) {
        int i = idx - 65536;
        int k = i >> 8, n = i & 255;
        v = W1[i]; ph = T1h; pl = T1l; o = n * 256 + k;
    } else {
        int i = idx - 131072;                    // < 8192
        int k = i >> 5, n = i & 31;
        v = W2[i]; ph = T2h; pl = T2l; o = n * 256 + k;
    }
    bf16_t h = (bf16_t)v;
    ph[o] = h;
    pl[o] = (bf16_t)(v - (float)h);
}

// ---------------- Persistent MFMA GEMM: B-hi in LDS, swapped operands ------
// Grid = 256 blocks x 1024 thr (16 waves: wr=w>>2 row 32-band, wc=w&3 col
// 64-band). B-hi (256x256 bf16 = 128KB) staged once frag-major; grid-stride
// over 128-row M-tiles. MFMA operands SWAPPED: accT[n][m] = mfma(Wfrag, Xfrag)
// so D: col(lane&15)=X-row, rows(kg*4+reg)=W-col -> each lane holds 4
// consecutive H columns of one row => 8B bf16x4 stores (was 32x 2B scalar).
// A_FP32: x hi/lo in-register -> 2 MFMA/frag; else exact bf16 -> 1.

template<bool A_FP32>
__global__ __launch_bounds__(1024) void k_gemm256_persist(
        const float* __restrict__ Af, const bf16_t* __restrict__ Ab,
        const bf16_t* __restrict__ Bth,
        const float* __restrict__ a_s, const float* __restrict__ a_d,
        bf16_t* __restrict__ Hb, float* __restrict__ As, float* __restrict__ Ad) {
    __shared__ __align__(16) bf16_t Bs[16][8][512];   // 131072 B
    __shared__ float redS[4][128], redD[4][128];      //   4096 B

    const int tid  = threadIdx.x;
    const int lane = tid & 63;
    const int w    = tid >> 6;       // 0..15
    const int wr   = w >> 2;         // 0..3: 32-row band
    const int wc   = w & 3;          // 0..3: 64-col band
    const int r16  = lane & 15;
    const int kg   = lane >> 4;      // 0..3
    const int colw = wc * 64;

    // ---- stage whole B-hi once: 128 wave-ops of 1KB, 8 per wave ----
    #pragma unroll
    for (int i = 0; i < 8; ++i) {
        int op   = w * 8 + i;        // 0..127
        int nsub = op >> 3;          // 0..15
        int kk   = op & 7;           // 0..7
        gll16(&Bth[(nsub * 16 + r16) * 256 + kk * 32 + kg * 8], &Bs[nsub][kk][0]);
    }

    float4 as4[4], ad4[4];
    #pragma unroll
    for (int n = 0; n < 4; ++n) {
        as4[n] = *(const float4*)&a_s[colw + n * 16 + kg * 4];
        ad4[n] = *(const float4*)&a_d[colw + n * 16 + kg * 4];
    }
    __syncthreads();   // drains staging vmcnt; B resident for whole kernel

    for (int tile = blockIdx.x; tile < N_TILES128; tile += GEMM_BLOCKS_P) {
        const int rowg = tile * 128 + wr * 32;
        int aoff[2];
        #pragma unroll
        for (int m = 0; m < 2; ++m) {
            int row = rowg + m * 16 + r16;
            if (A_FP32 && row >= N_NODES) row = N_NODES - 1;  // fp32 src unpadded
            aoff[m] = row * 256 + kg * 8;
        }

        f32x4 accT[4][2] = {};   // [n][m]
        #pragma unroll
        for (int kk = 0; kk < 8; ++kk) {
            const int k0 = kk * 32;
            bf16x8 xh[2], xl[2], wf[4];
            #pragma unroll
            for (int n = 0; n < 4; ++n)
                wf[n] = *(const bf16x8*)&Bs[wc * 4 + n][kk][lane * 8];
            if constexpr (A_FP32) {
                #pragma unroll
                for (int m = 0; m < 2; ++m) {
                    float4 v0 = *(const float4*)(Af + aoff[m] + k0);
                    float4 v1 = *(const float4*)(Af + aoff[m] + k0 + 4);
                    float f[8] = {v0.x, v0.y, v0.z, v0.w, v1.x, v1.y, v1.z, v1.w};
                    #pragma unroll
                    for (int i = 0; i < 8; ++i) {
                        bf16_t h = (bf16_t)f[i];
                        xh[m][i] = h;
                        xl[m][i] = (bf16_t)(f[i] - (float)h);
                    }
                }
            } else {
                #pragma unroll
                for (int m = 0; m < 2; ++m)
                    xh[m] = *(const bf16x8*)(Ab + aoff[m] + k0);
            }
            #pragma unroll
            for (int n = 0; n < 4; ++n) {
                #pragma unroll
                for (int m = 0; m < 2; ++m) {
                    accT[n][m] = __builtin_amdgcn_mfma_f32_16x16x32_bf16(wf[n], xh[m], accT[n][m], 0, 0, 0);
                    if constexpr (A_FP32)
                        accT[n][m] = __builtin_amdgcn_mfma_f32_16x16x32_bf16(wf[n], xl[m], accT[n][m], 0, 0, 0);
                }
            }
        }

        // ---- epilogue: lane holds H[row=r16-band][4 consecutive cols] ----
        #pragma unroll
        for (int m = 0; m < 2; ++m) {
            int row = rowg + m * 16 + r16;
            bool ok = row < N_NODES;
            float ss = 0.f, sd = 0.f;
            #pragma unroll
            for (int n = 0; n < 4; ++n) {
                f32x4 v = accT[n][m];
                if (ok) {
                    bf16x4 st = {(bf16_t)v[0], (bf16_t)v[1], (bf16_t)v[2], (bf16_t)v[3]};
                    *(bf16x4*)&Hb[row * 256 + colw + n * 16 + kg * 4] = st;
                }
                ss += v[0] * as4[n].x + v[1] * as4[n].y + v[2] * as4[n].z + v[3] * as4[n].w;
                sd += v[0] * ad4[n].x + v[1] * ad4[n].y + v[2] * ad4[n].z + v[3] * ad4[n].w;
            }
            ss += __shfl_xor(ss, 16); ss += __shfl_xor(ss, 32);
            sd += __shfl_xor(sd, 16); sd += __shfl_xor(sd, 32);
            if (kg == 0) {
                redS[wc][wr * 32 + m * 16 + r16] = ss;
                redD[wc][wr * 32 + m * 16 + r16] = sd;
            }
        }
        __syncthreads();
        if (tid < 128) {
            int row = tile * 128 + tid;
            if (row < N_NODES) {
                As[row] = redS[0][tid] + redS[1][tid] + redS[2][tid] + redS[3][tid];
                Ad[row] = redD[0][tid] + redD[1][tid] + redD[2][tid] + redD[3][tid];
            }
        }
        __syncthreads();
    }
}

// ---------------- GEMM 32-out (layer 2), swapped operands ------------------
// Block 256 thr = 4 waves; wave = 64 rows x all 32 cols; accT[n][m].
// Lane holds 4 consecutive cols of one row -> float4 stores.

__global__ __launch_bounds__(256) void k_gemm32_mfma(
        const bf16_t* __restrict__ Ab,                          // [PAD_ROWS][256]
        const bf16_t* __restrict__ Bth, const bf16_t* __restrict__ Btl,  // [32][256]
        const float* __restrict__ a_s, const float* __restrict__ a_d,
        float* __restrict__ Hc, float* __restrict__ As, float* __restrict__ Ad) {
    const int tid  = threadIdx.x;
    const int lane = tid & 63;
    const int wv   = tid >> 6;
    const int r16  = lane & 15;
    const int kg   = lane >> 4;
    const int rowg = blockIdx.x * 256 + wv * 64;

    int aoff[4], boff[2];
    #pragma unroll
    for (int m = 0; m < 4; ++m) {
        int row = rowg + m * 16 + r16;
        if (row >= N_NODES) row = N_NODES - 1;   // grid overshoots PAD_ROWS
        aoff[m] = row * 256 + kg * 8;
    }
    #pragma unroll
    for (int n = 0; n < 2; ++n)
        boff[n] = (n * 16 + r16) * 256 + kg * 8;

    f32x4 accT[2][4] = {};   // [n][m]

    #pragma unroll
    for (int kk = 0; kk < 8; ++kk) {
        const int k0 = kk * 32;
        bf16x8 ah[4], bh[2], bl[2];
        #pragma unroll
        for (int m = 0; m < 4; ++m)
            ah[m] = *(const bf16x8*)(Ab + aoff[m] + k0);
        #pragma unroll
        for (int n = 0; n < 2; ++n) {
            bh[n] = *(const bf16x8*)(Bth + boff[n] + k0);
            bl[n] = *(const bf16x8*)(Btl + boff[n] + k0);
        }
        #pragma unroll
        for (int n = 0; n < 2; ++n) {
            #pragma unroll
            for (int m = 0; m < 4; ++m) {
                accT[n][m] = __builtin_amdgcn_mfma_f32_16x16x32_bf16(bh[n], ah[m], accT[n][m], 0, 0, 0);
                accT[n][m] = __builtin_amdgcn_mfma_f32_16x16x32_bf16(bl[n], ah[m], accT[n][m], 0, 0, 0);
            }
        }
    }

    float4 as4[2], ad4[2];
    #pragma unroll
    for (int n = 0; n < 2; ++n) {
        as4[n] = *(const float4*)&a_s[n * 16 + kg * 4];
        ad4[n] = *(const float4*)&a_d[n * 16 + kg * 4];
    }
    #pragma unroll
    for (int m = 0; m < 4; ++m) {
        int row = rowg + m * 16 + r16;
        bool ok = row < N_NODES;
        float ss = 0.f, sd = 0.f;
        #pragma unroll
        for (int n = 0; n < 2; ++n) {
            f32x4 v = accT[n][m];
            if (ok) {
                float4 st = {v[0], v[1], v[2], v[3]};
                *(float4*)&Hc[row * 32 + n * 16 + kg * 4] = st;
            }
            ss += v[0] * as4[n].x + v[1] * as4[n].y + v[2] * as4[n].z + v[3] * as4[n].w;
            sd += v[0] * ad4[n].x + v[1] * ad4[n].y + v[2] * ad4[n].z + v[3] * ad4[n].w;
        }
        ss += __shfl_xor(ss, 16); ss += __shfl_xor(ss, 32);
        sd += __shfl_xor(sd, 16); sd += __shfl_xor(sd, 32);
        if (ok && kg == 0) { As[row] = ss; Ad[row] = sd; }
    }
}

// ---------------- Attention: per-edge exp weights + per-node 1/denom ----------------

__global__ __launch_bounds__(256) void k_attn(
        const float* __restrict__ As, const float* __restrict__ Ad,
        const int* __restrict__ offs, const int* __restrict__ cnts,
        const int* __restrict__ srcs,
        int2* __restrict__ meta, float* __restrict__ inv) {
    const int lane = threadIdx.x & 63;
    int node = blockIdx.x * 4 + (threadIdx.x >> 6);
    if (node >= N_NODES) return;
    node = __builtin_amdgcn_readfirstlane(node);
    const int start = offs[node];
    const int cnt   = cnts[node];
    const float ad  = Ad[node];

    float m = -1e30f;
    for (int base = 0; base < cnt; base += 64) {
        int i = base + lane;
        if (i < cnt) {
            float e = As[srcs[start + i]] + ad;
            e = e > 0.f ? e : NEG_SLOPE * e;
            m = fmaxf(m, e);
        }
    }
    #pragma unroll
    for (int o = 32; o; o >>= 1) m = fmaxf(m, __shfl_xor(m, o));

    float denom = 0.f;
    for (int base = 0; base < cnt; base += 64) {
        int i = base + lane;
        if (i < cnt) {
            int s = srcs[start + i];
            float e = As[s] + ad;
            e = e > 0.f ? e : NEG_SLOPE * e;
            float p = __expf(e - m);
            denom += p;
            meta[start + i] = make_int2(s, __float_as_int(p));
        }
    }
    #pragma unroll
    for (int o = 32; o; o >>= 1) denom += __shfl_xor(denom, o);
    if (lane == 0) inv[node] = 1.f / denom;
}

// ---------------- Gather (256-wide bf16), fused bias + swish ----------------

__global__ __launch_bounds__(256) void k_gather256(
        const bf16_t* __restrict__ Hb, const int2* __restrict__ meta,
        const int* __restrict__ offs, const int* __restrict__ cnts,
        const float* __restrict__ inv,
        const float* __restrict__ bias, bf16_t* __restrict__ Hout) {
    const int lane = threadIdx.x & 63;
    int node = blockIdx.x * 4 + (threadIdx.x >> 6);
    if (node >= N_NODES) return;
    node = __builtin_amdgcn_readfirstlane(node);
    const int start = offs[node];
    const int cnt   = cnts[node];
    const float iv  = inv[node];
    const int c0 = lane * 4;

    float4 acc = {0.f, 0.f, 0.f, 0.f};
    for (int j = 0; j < cnt; j += 4) {
        int2 mp[4];
        #pragma unroll
        for (int k = 0; k < 4; ++k) mp[k] = meta[start + j + k];  // pad-safe
        #pragma unroll
        for (int k = 0; k < 4; ++k) {
            float p = (j + k < cnt) ? __int_as_float(mp[k].y) : 0.f;
            bf16x4 hv = *(const bf16x4*)&Hb[mp[k].x * 256 + c0];
            acc.x += p * (float)hv[0];
            acc.y += p * (float)hv[1];
            acc.z += p * (float)hv[2];
            acc.w += p * (float)hv[3];
        }
    }

    const float4 bv = *(const float4*)&bias[c0];
    float4 o4;
    o4.x = acc.x * iv + bv.x;
    o4.y = acc.y * iv + bv.y;
    o4.z = acc.z * iv + bv.z;
    o4.w = acc.w * iv + bv.w;
    o4.x = o4.x / (1.f + __expf(-o4.x));
    o4.y = o4.y / (1.f + __expf(-o4.y));
    o4.z = o4.z / (1.f + __expf(-o4.z));
    o4.w = o4.w / (1.f + __expf(-o4.w));
    bf16x4 st = {(bf16_t)o4.x, (bf16_t)o4.y, (bf16_t)o4.z, (bf16_t)o4.w};
    *(bf16x4*)&Hout[node * 256 + c0] = st;
}

// ---------------- Final gather (32-wide fp32) + bias + log_softmax ----------------

__global__ __launch_bounds__(256) void k_gather_final(
        const float* __restrict__ Hc,   // [N][32]
        const int2* __restrict__ meta,
        const int* __restrict__ offs, const int* __restrict__ cnts,
        const float* __restrict__ inv,
        const float* __restrict__ bias, float* __restrict__ out) {
    const int lane = threadIdx.x & 63;
    int node = blockIdx.x * 4 + (threadIdx.x >> 6);
    if (node >= N_NODES) return;
    node = __builtin_amdgcn_readfirstlane(node);
    const int start = offs[node];
    const int cnt   = cnts[node];
    const float iv  = inv[node];
    const int c = lane & 31;

    float acc = 0.f;
    for (int j = 0; j < cnt; j += 4) {
        int2 mp[4];
        #pragma unroll
        for (int k = 0; k < 4; ++k) mp[k] = meta[start + j + k];
        #pragma unroll
        for (int k = 0; k < 4; ++k) {
            float p = (j + k < cnt) ? __int_as_float(mp[k].y) : 0.f;
            acc += p * Hc[mp[k].x * 32 + c];
        }
    }

    float v = acc * iv + bias[c];
    float mm = v;
    #pragma unroll
    for (int o = 16; o; o >>= 1) mm = fmaxf(mm, __shfl_xor(mm, o));
    float ex = __expf(v - mm), sum = ex;
    #pragma unroll
    for (int o = 16; o; o >>= 1) sum += __shfl_xor(sum, o);
    float r = v - mm - __logf(sum);
    if (lane < 32) out[node * 32 + c] = r;
}

// ---------------- launch ----------------

extern "C" void kernel_launch(void* const* d_in, const int* in_sizes, int n_in,
                              void* d_out, int out_size, void* d_ws, size_t ws_size,
                              hipStream_t stream) {
    const float* x   = (const float*)d_in[0];
    const int*   ei  = (const int*)  d_in[1];
    const float* W0  = (const float*)d_in[2];
    const float* as0 = (const float*)d_in[3];
    const float* ad0 = (const float*)d_in[4];
    const float* b0  = (const float*)d_in[5];
    const float* W1  = (const float*)d_in[6];
    const float* as1 = (const float*)d_in[7];
    const float* ad1 = (const float*)d_in[8];
    const float* b1  = (const float*)d_in[9];
    const float* W2  = (const float*)d_in[10];
    const float* as2 = (const float*)d_in[11];
    const float* ad2 = (const float*)d_in[12];
    const float* b2  = (const float*)d_in[13];
    float* out = (float*)d_out;

    char* ws = (char*)d_ws;
    // padded bf16 feature buffers: PAD_ROWS*256*2 = 25,624,576 B each
    bf16_t* hA_b  = (bf16_t*)(ws + 0);
    bf16_t* hB_b  = (bf16_t*)(ws + 25624576);
    float*  hC    = (float*) (ws + 51249152);   //  6,400,000
    float*  As    = (float*) (ws + 57649152);
    float*  Ad    = (float*) (ws + 57849152);
    float*  inv   = (float*) (ws + 58049152);
    int*    cnts  = (int*)   (ws + 58249152);
    int*    offs  = (int*)   (ws + 58449152);
    int*    cursor= (int*)   (ws + 58649152);
    int*    srcs  = (int*)   (ws + 58849152);   //  1,800,000
    int2*   meta  = (int2*)  (ws + 60649152);   //  3,600,032 (E_TOT+4)
    int*    bsum  = (int*)   (ws + 64249184);   //      1,024
    bf16_t* Wth0  = (bf16_t*)(ws + 64250208);   //    131,072
    bf16_t* Wtl0  = (bf16_t*)(ws + 64381280);   //    131,072
    bf16_t* Wth1  = (bf16_t*)(ws + 64512352);   //    131,072
    bf16_t* Wtl1  = (bf16_t*)(ws + 64643424);   //    131,072
    bf16_t* Wth2  = (bf16_t*)(ws + 64774496);   //     16,384
    bf16_t* Wtl2  = (bf16_t*)(ws + 64790880);   //     16,384 -> end 64,807,264

    const int NB = (N_NODES + 255) / 256;       // 196

    hipMemsetAsync(cnts,   0, N_NODES * sizeof(int), stream);
    hipMemsetAsync(cursor, 0, N_NODES * sizeof(int), stream);
    hipMemsetAsync((char*)meta + (size_t)E_TOT * 8, 0, 32, stream);  // pad

    k_hist     <<<(E_TOT + 255) / 256, 256, 0, stream>>>(ei, cnts);
    k_scan1    <<<NB, 256, 0, stream>>>(cnts, offs, bsum);
    k_scan2    <<<1, 256, 0, stream>>>(bsum, NB);
    k_scan3    <<<NB, 256, 0, stream>>>(offs, bsum);
    k_scatter  <<<(E_TOT + 255) / 256, 256, 0, stream>>>(ei, offs, cursor, srcs);
    k_split_all<<<544, 256, 0, stream>>>(W0, W1, W2, Wth0, Wtl0, Wth1, Wtl1, Wth2, Wtl2);

    const int AGG_BLOCKS = (N_NODES + 3) / 4;   // 12500

    // layer 0 (A = x fp32, in-register hi/lo split; W0 hi-only, LDS-resident)
    k_gemm256_persist<true><<<GEMM_BLOCKS_P, 1024, 0, stream>>>(x, nullptr, Wth0, as0, ad0, hA_b, As, Ad);
    k_attn<<<AGG_BLOCKS, 256, 0, stream>>>(As, Ad, offs, cnts, srcs, meta, inv);
    k_gather256<<<AGG_BLOCKS, 256, 0, stream>>>(hA_b, meta, offs, cnts, inv, b0, hB_b);
    // layer 1 (A exact bf16; W1 hi-only, LDS-resident)
    k_gemm256_persist<false><<<GEMM_BLOCKS_P, 1024, 0, stream>>>(nullptr, hB_b, Wth1, as1, ad1, hA_b, As, Ad);
    k_attn<<<AGG_BLOCKS, 256, 0, stream>>>(As, Ad, offs, cnts, srcs, meta, inv);
    k_gather256<<<AGG_BLOCKS, 256, 0, stream>>>(hA_b, meta, offs, cnts, inv, b1, hB_b);
    // layer 2 (+ fused log_softmax; W2 keeps hi+lo)
    k_gemm32_mfma<<<NB, 256, 0, stream>>>(hB_b, Wth2, Wtl2, as2, ad2, hC, As, Ad);
    k_attn<<<AGG_BLOCKS, 256, 0, stream>>>(As, Ad, offs, cnts, srcs, meta, inv);
    k_gather_final<<<AGG_BLOCKS, 256, 0, stream>>>(hC, meta, offs, cnts, inv, b2, out);
}

// Round 11
// 281.051 us; speedup vs baseline: 1.3062x; 1.0187x over previous
//
#include <hip/hip_runtime.h>
#include <math.h>

#define N_NODES 50000
#define PAD_ROWS 50176                 // 392 * 128
#define N_TILES128 392                 // 128-row tiles
#define E_RAW   400000
#define E_TOT   (E_RAW + N_NODES)      // 450000 incl. self loops
#define NEG_SLOPE 0.2f

typedef __bf16 bf16_t;
typedef bf16_t bf16x8 __attribute__((ext_vector_type(8)));
typedef bf16_t bf16x4 __attribute__((ext_vector_type(4)));
typedef float  f32x4  __attribute__((ext_vector_type(4)));

__device__ __forceinline__ void gll16(const void* g, void* l) {
    __builtin_amdgcn_global_load_lds(
        (const __attribute__((address_space(1))) void*)g,
        (__attribute__((address_space(3))) void*)l, 16, 0, 0);
}

// ---------------- CSR build ----------------

__global__ void k_hist(const int* __restrict__ ei, int* __restrict__ cnt) {
    int e = blockIdx.x * 256 + threadIdx.x;
    if (e >= E_TOT) return;
    int dst = (e < E_RAW) ? ei[E_RAW + e] : (e - E_RAW);
    atomicAdd(&cnt[dst], 1);
}

__global__ void k_scan1(const int* __restrict__ cnt, int* __restrict__ offs,
                        int* __restrict__ bsum) {
    __shared__ int s[256];
    int i = blockIdx.x * 256 + threadIdx.x;
    int v = (i < N_NODES) ? cnt[i] : 0;
    s[threadIdx.x] = v;
    __syncthreads();
    for (int d = 1; d < 256; d <<= 1) {
        int t = (threadIdx.x >= d) ? s[threadIdx.x - d] : 0;
        __syncthreads();
        s[threadIdx.x] += t;
        __syncthreads();
    }
    if (i < N_NODES) offs[i] = s[threadIdx.x] - v;   // exclusive
    if (threadIdx.x == 255) bsum[blockIdx.x] = s[255];
}

__global__ void k_scan2(int* __restrict__ bsum, int nb) {
    __shared__ int s[256];
    int v = (threadIdx.x < nb) ? bsum[threadIdx.x] : 0;
    s[threadIdx.x] = v;
    __syncthreads();
    for (int d = 1; d < 256; d <<= 1) {
        int t = (threadIdx.x >= d) ? s[threadIdx.x - d] : 0;
        __syncthreads();
        s[threadIdx.x] += t;
        __syncthreads();
    }
    if (threadIdx.x < nb) bsum[threadIdx.x] = s[threadIdx.x] - v;  // exclusive
}

__global__ void k_scan3(int* __restrict__ offs, const int* __restrict__ bsum) {
    int i = blockIdx.x * 256 + threadIdx.x;
    if (i < N_NODES) offs[i] += bsum[blockIdx.x];
}

__global__ void k_scatter(const int* __restrict__ ei, const int* __restrict__ offs,
                          int* __restrict__ cursor, int* __restrict__ srcs) {
    int e = blockIdx.x * 256 + threadIdx.x;
    if (e >= E_TOT) return;
    int src, dst;
    if (e < E_RAW) { src = ei[e]; dst = ei[E_RAW + e]; }
    else           { src = dst = e - E_RAW; }
    int pos = offs[dst] + atomicAdd(&cursor[dst], 1);
    srcs[pos] = src;
}

// ---------------- W splits: all three layers in one launch ----------------
// W0,W1: [256][256] -> [n][k] bf16 hi/lo.  W2: [256][32] -> [32][256] hi/lo.
// (lo of W0/W1 unused - hi-only LDS residency in the big GEMMs.)

__global__ void k_split_all(const float* __restrict__ W0, const float* __restrict__ W1,
                            const float* __restrict__ W2,
                            bf16_t* __restrict__ T0h, bf16_t* __restrict__ T0l,
                            bf16_t* __restrict__ T1h, bf16_t* __restrict__ T1l,
                            bf16_t* __restrict__ T2h, bf16_t* __restrict__ T2l) {
    int idx = blockIdx.x * 256 + threadIdx.x;    // 139264 total
    float v; bf16_t *ph, *pl; int o;
    if (idx < 65536) {
        int k = idx >> 8, n = idx & 255;
        v = W0[idx]; ph = T0h; pl = T0l; o = n * 256 + k;
    } else if (idx < 131072) {
        int i = idx - 65536;
        int k = i >> 8, n = i & 255;
        v = W1[i]; ph = T1h; pl = T1l; o = n * 256 + k;
    } else {
        int i = idx - 131072;                    // < 8192
        int k = i >> 5, n = i & 31;
        v = W2[i]; ph = T2h; pl = T2l; o = n * 256 + k;
    }
    bf16_t h = (bf16_t)v;
    ph[o] = h;
    pl[o] = (bf16_t)(v - (float)h);
}

// ---------------- MFMA GEMM: A register-resident, one load burst per tile ---
// 512 thr = 8 waves; block tile = 128 rows; wave w owns rows w*16..+15 x ALL
// 256 cols (16 n-frags, accT[16] = 64 VGPR). B-hi (128KB) staged once into
// LDS frag-major (slot=lane, conflict-free). A for the WHOLE tile loaded in
// one upfront burst into registers (xh[8]/xl[8]); K-loop then has ZERO global
// loads and ZERO barriers -> single latency exposure per tile (vs 8 in R10).
// Swapped-operand MFMA (R10-verified): accT[n] = mfma(Wfrag, Xfrag) => lane
// holds 4 consecutive H cols of one row -> bf16x4 stores; full-row alpha dot
// in-wave (shfl_xor 16/32), no cross-wave reduce.
// A_FP32: x hi/lo split in-register -> 2 MFMA/frag; else exact bf16 -> 1.

template<bool A_FP32>
__global__ __launch_bounds__(512) void k_gemm256_reg(
        const float* __restrict__ Af, const bf16_t* __restrict__ Ab,
        const bf16_t* __restrict__ Bth,
        const float* __restrict__ a_s, const float* __restrict__ a_d,
        bf16_t* __restrict__ Hb, float* __restrict__ As, float* __restrict__ Ad) {
    __shared__ __align__(16) bf16_t Bs[16][8][512];   // 131072 B

    const int tid  = threadIdx.x;
    const int lane = tid & 63;
    const int w    = tid >> 6;       // 0..7: 16-row band
    const int r16  = lane & 15;
    const int kg   = lane >> 4;      // 0..3

    // ---- stage whole B-hi once: 128 wave-ops of 1KB, 16 per wave ----
    #pragma unroll
    for (int i = 0; i < 16; ++i) {
        int op   = w * 16 + i;       // 0..127
        int nsub = op >> 3;          // 0..15
        int kk   = op & 7;           // 0..7
        gll16(&Bth[(nsub * 16 + r16) * 256 + kk * 32 + kg * 8], &Bs[nsub][kk][0]);
    }

    const int row  = blockIdx.x * 128 + w * 16 + r16;
    const int rowc = min(row, N_NODES - 1);
    const bool ok  = row < N_NODES;

    // ---- A burst: whole tile-row K into registers (one latency exposure) ----
    bf16x8 xh[8], xl[8];
    if constexpr (A_FP32) {
        const float* abase = Af + rowc * 256 + kg * 8;
        float4 ra0[8], ra1[8];
        #pragma unroll
        for (int kk = 0; kk < 8; ++kk) {
            ra0[kk] = *(const float4*)(abase + kk * 32);
            ra1[kk] = *(const float4*)(abase + kk * 32 + 4);
        }
        #pragma unroll
        for (int kk = 0; kk < 8; ++kk) {
            float f[8] = {ra0[kk].x, ra0[kk].y, ra0[kk].z, ra0[kk].w,
                          ra1[kk].x, ra1[kk].y, ra1[kk].z, ra1[kk].w};
            #pragma unroll
            for (int i = 0; i < 8; ++i) {
                bf16_t h = (bf16_t)f[i];
                xh[kk][i] = h;
                xl[kk][i] = (bf16_t)(f[i] - (float)h);
            }
        }
    } else {
        const bf16_t* abase = Ab + rowc * 256 + kg * 8;
        #pragma unroll
        for (int kk = 0; kk < 8; ++kk)
            xh[kk] = *(const bf16x8*)(abase + kk * 32);
    }
    __syncthreads();   // B resident (A burst overlapped with staging drain)

    // ---- K-loop: registers + LDS only, no barriers ----
    f32x4 accT[16] = {};
    #pragma unroll
    for (int kk = 0; kk < 8; ++kk) {
        #pragma unroll
        for (int n = 0; n < 16; ++n) {
            bf16x8 wf = *(const bf16x8*)&Bs[n][kk][lane * 8];
            accT[n] = __builtin_amdgcn_mfma_f32_16x16x32_bf16(wf, xh[kk], accT[n], 0, 0, 0);
            if constexpr (A_FP32)
                accT[n] = __builtin_amdgcn_mfma_f32_16x16x32_bf16(wf, xl[kk], accT[n], 0, 0, 0);
        }
    }

    // ---- epilogue: lane holds H[row][n*16+kg*4 .. +3]; full-row alpha ----
    float ss = 0.f, sd = 0.f;
    #pragma unroll
    for (int n = 0; n < 16; ++n) {
        f32x4 v = accT[n];
        if (ok) {
            bf16x4 st = {(bf16_t)v[0], (bf16_t)v[1], (bf16_t)v[2], (bf16_t)v[3]};
            *(bf16x4*)&Hb[row * 256 + n * 16 + kg * 4] = st;
        }
        float4 a4 = *(const float4*)&a_s[n * 16 + kg * 4];
        float4 d4 = *(const float4*)&a_d[n * 16 + kg * 4];
        ss += v[0] * a4.x + v[1] * a4.y + v[2] * a4.z + v[3] * a4.w;
        sd += v[0] * d4.x + v[1] * d4.y + v[2] * d4.z + v[3] * d4.w;
    }
    ss += __shfl_xor(ss, 16); ss += __shfl_xor(ss, 32);
    sd += __shfl_xor(sd, 16); sd += __shfl_xor(sd, 32);
    if (ok && kg == 0) { As[row] = ss; Ad[row] = sd; }
}

// ---------------- GEMM 32-out (layer 2), swapped operands ------------------
// Block 256 thr = 4 waves; wave = 64 rows x all 32 cols; accT[n][m].
// Lane holds 4 consecutive cols of one row -> float4 stores.

__global__ __launch_bounds__(256) void k_gemm32_mfma(
        const bf16_t* __restrict__ Ab,                          // [PAD_ROWS][256]
        const bf16_t* __restrict__ Bth, const bf16_t* __restrict__ Btl,  // [32][256]
        const float* __restrict__ a_s, const float* __restrict__ a_d,
        float* __restrict__ Hc, float* __restrict__ As, float* __restrict__ Ad) {
    const int tid  = threadIdx.x;
    const int lane = tid & 63;
    const int wv   = tid >> 6;
    const int r16  = lane & 15;
    const int kg   = lane >> 4;
    const int rowg = blockIdx.x * 256 + wv * 64;

    int aoff[4], boff[2];
    #pragma unroll
    for (int m = 0; m < 4; ++m) {
        int row = rowg + m * 16 + r16;
        if (row >= N_NODES) row = N_NODES - 1;
        aoff[m] = row * 256 + kg * 8;
    }
    #pragma unroll
    for (int n = 0; n < 2; ++n)
        boff[n] = (n * 16 + r16) * 256 + kg * 8;

    f32x4 accT[2][4] = {};   // [n][m]

    #pragma unroll
    for (int kk = 0; kk < 8; ++kk) {
        const int k0 = kk * 32;
        bf16x8 ah[4], bh[2], bl[2];
        #pragma unroll
        for (int m = 0; m < 4; ++m)
            ah[m] = *(const bf16x8*)(Ab + aoff[m] + k0);
        #pragma unroll
        for (int n = 0; n < 2; ++n) {
            bh[n] = *(const bf16x8*)(Bth + boff[n] + k0);
            bl[n] = *(const bf16x8*)(Btl + boff[n] + k0);
        }
        #pragma unroll
        for (int n = 0; n < 2; ++n) {
            #pragma unroll
            for (int m = 0; m < 4; ++m) {
                accT[n][m] = __builtin_amdgcn_mfma_f32_16x16x32_bf16(bh[n], ah[m], accT[n][m], 0, 0, 0);
                accT[n][m] = __builtin_amdgcn_mfma_f32_16x16x32_bf16(bl[n], ah[m], accT[n][m], 0, 0, 0);
            }
        }
    }

    float4 as4[2], ad4[2];
    #pragma unroll
    for (int n = 0; n < 2; ++n) {
        as4[n] = *(const float4*)&a_s[n * 16 + kg * 4];
        ad4[n] = *(const float4*)&a_d[n * 16 + kg * 4];
    }
    #pragma unroll
    for (int m = 0; m < 4; ++m) {
        int row = rowg + m * 16 + r16;
        bool ok = row < N_NODES;
        float ss = 0.f, sd = 0.f;
        #pragma unroll
        for (int n = 0; n < 2; ++n) {
            f32x4 v = accT[n][m];
            if (ok) {
                float4 st = {v[0], v[1], v[2], v[3]};
                *(float4*)&Hc[row * 32 + n * 16 + kg * 4] = st;
            }
            ss += v[0] * as4[n].x + v[1] * as4[n].y + v[2] * as4[n].z + v[3] * as4[n].w;
            sd += v[0] * ad4[n].x + v[1] * ad4[n].y + v[2] * ad4[n].z + v[3] * ad4[n].w;
        }
        ss += __shfl_xor(ss, 16); ss += __shfl_xor(ss, 32);
        sd += __shfl_xor(sd, 16); sd += __shfl_xor(sd, 32);
        if (ok && kg == 0) { As[row] = ss; Ad[row] = sd; }
    }
}

// ---------------- Attention: per-edge exp weights + per-node 1/denom ----------------

__global__ __launch_bounds__(256) void k_attn(
        const float* __restrict__ As, const float* __restrict__ Ad,
        const int* __restrict__ offs, const int* __restrict__ cnts,
        const int* __restrict__ srcs,
        int2* __restrict__ meta, float* __restrict__ inv) {
    const int lane = threadIdx.x & 63;
    int node = blockIdx.x * 4 + (threadIdx.x >> 6);
    if (node >= N_NODES) return;
    node = __builtin_amdgcn_readfirstlane(node);
    const int start = offs[node];
    const int cnt   = cnts[node];
    const float ad  = Ad[node];

    float m = -1e30f;
    for (int base = 0; base < cnt; base += 64) {
        int i = base + lane;
        if (i < cnt) {
            float e = As[srcs[start + i]] + ad;
            e = e > 0.f ? e : NEG_SLOPE * e;
            m = fmaxf(m, e);
        }
    }
    #pragma unroll
    for (int o = 32; o; o >>= 1) m = fmaxf(m, __shfl_xor(m, o));

    float denom = 0.f;
    for (int base = 0; base < cnt; base += 64) {
        int i = base + lane;
        if (i < cnt) {
            int s = srcs[start + i];
            float e = As[s] + ad;
            e = e > 0.f ? e : NEG_SLOPE * e;
            float p = __expf(e - m);
            denom += p;
            meta[start + i] = make_int2(s, __float_as_int(p));
        }
    }
    #pragma unroll
    for (int o = 32; o; o >>= 1) denom += __shfl_xor(denom, o);
    if (lane == 0) inv[node] = 1.f / denom;
}

// ---------------- Gather (256-wide bf16), fused bias + swish ----------------

__global__ __launch_bounds__(256) void k_gather256(
        const bf16_t* __restrict__ Hb, const int2* __restrict__ meta,
        const int* __restrict__ offs, const int* __restrict__ cnts,
        const float* __restrict__ inv,
        const float* __restrict__ bias, bf16_t* __restrict__ Hout) {
    const int lane = threadIdx.x & 63;
    int node = blockIdx.x * 4 + (threadIdx.x >> 6);
    if (node >= N_NODES) return;
    node = __builtin_amdgcn_readfirstlane(node);
    const int start = offs[node];
    const int cnt   = cnts[node];
    const float iv  = inv[node];
    const int c0 = lane * 4;

    float4 acc = {0.f, 0.f, 0.f, 0.f};
    for (int j = 0; j < cnt; j += 4) {
        int2 mp[4];
        #pragma unroll
        for (int k = 0; k < 4; ++k) mp[k] = meta[start + j + k];  // pad-safe
        #pragma unroll
        for (int k = 0; k < 4; ++k) {
            float p = (j + k < cnt) ? __int_as_float(mp[k].y) : 0.f;
            bf16x4 hv = *(const bf16x4*)&Hb[mp[k].x * 256 + c0];
            acc.x += p * (float)hv[0];
            acc.y += p * (float)hv[1];
            acc.z += p * (float)hv[2];
            acc.w += p * (float)hv[3];
        }
    }

    const float4 bv = *(const float4*)&bias[c0];
    float4 o4;
    o4.x = acc.x * iv + bv.x;
    o4.y = acc.y * iv + bv.y;
    o4.z = acc.z * iv + bv.z;
    o4.w = acc.w * iv + bv.w;
    o4.x = o4.x / (1.f + __expf(-o4.x));
    o4.y = o4.y / (1.f + __expf(-o4.y));
    o4.z = o4.z / (1.f + __expf(-o4.z));
    o4.w = o4.w / (1.f + __expf(-o4.w));
    bf16x4 st = {(bf16_t)o4.x, (bf16_t)o4.y, (bf16_t)o4.z, (bf16_t)o4.w};
    *(bf16x4*)&Hout[node * 256 + c0] = st;
}

// ---------------- Final gather (32-wide fp32) + bias + log_softmax ----------------

__global__ __launch_bounds__(256) void k_gather_final(
        const float* __restrict__ Hc,   // [N][32]
        const int2* __restrict__ meta,
        const int* __restrict__ offs, const int* __restrict__ cnts,
        const float* __restrict__ inv,
        const float* __restrict__ bias, float* __restrict__ out) {
    const int lane = threadIdx.x & 63;
    int node = blockIdx.x * 4 + (threadIdx.x >> 6);
    if (node >= N_NODES) return;
    node = __builtin_amdgcn_readfirstlane(node);
    const int start = offs[node];
    const int cnt   = cnts[node];
    const float iv  = inv[node];
    const int c = lane & 31;

    float acc = 0.f;
    for (int j = 0; j < cnt; j += 4) {
        int2 mp[4];
        #pragma unroll
        for (int k = 0; k < 4; ++k) mp[k] = meta[start + j + k];
        #pragma unroll
        for (int k = 0; k < 4; ++k) {
            float p = (j + k < cnt) ? __int_as_float(mp[k].y) : 0.f;
            acc += p * Hc[mp[k].x * 32 + c];
        }
    }

    float v = acc * iv + bias[c];
    float mm = v;
    #pragma unroll
    for (int o = 16; o; o >>= 1) mm = fmaxf(mm, __shfl_xor(mm, o));
    float ex = __expf(v - mm), sum = ex;
    #pragma unroll
    for (int o = 16; o; o >>= 1) sum += __shfl_xor(sum, o);
    float r = v - mm - __logf(sum);
    if (lane < 32) out[node * 32 + c] = r;
}

// ---------------- launch ----------------

extern "C" void kernel_launch(void* const* d_in, const int* in_sizes, int n_in,
                              void* d_out, int out_size, void* d_ws, size_t ws_size,
                              hipStream_t stream) {
    const float* x   = (const float*)d_in[0];
    const int*   ei  = (const int*)  d_in[1];
    const float* W0  = (const float*)d_in[2];
    const float* as0 = (const float*)d_in[3];
    const float* ad0 = (const float*)d_in[4];
    const float* b0  = (const float*)d_in[5];
    const float* W1  = (const float*)d_in[6];
    const float* as1 = (const float*)d_in[7];
    const float* ad1 = (const float*)d_in[8];
    const float* b1  = (const float*)d_in[9];
    const float* W2  = (const float*)d_in[10];
    const float* as2 = (const float*)d_in[11];
    const float* ad2 = (const float*)d_in[12];
    const float* b2  = (const float*)d_in[13];
    float* out = (float*)d_out;

    char* ws = (char*)d_ws;
    // padded bf16 feature buffers: PAD_ROWS*256*2 = 25,690,112 B each
    bf16_t* hA_b  = (bf16_t*)(ws + 0);
    bf16_t* hB_b  = (bf16_t*)(ws + 25690112);
    float*  hC    = (float*) (ws + 51380224);   //  6,400,000
    float*  As    = (float*) (ws + 57780224);
    float*  Ad    = (float*) (ws + 57980224);
    float*  inv   = (float*) (ws + 58180224);
    int*    cnts  = (int*)   (ws + 58380224);
    int*    offs  = (int*)   (ws + 58580224);
    int*    cursor= (int*)   (ws + 58780224);
    int*    srcs  = (int*)   (ws + 58980224);   //  1,800,000
    int2*   meta  = (int2*)  (ws + 60780224);   //  3,600,032 (E_TOT+4)
    int*    bsum  = (int*)   (ws + 64380256);   //      1,024
    bf16_t* Wth0  = (bf16_t*)(ws + 64381280);   //    131,072
    bf16_t* Wtl0  = (bf16_t*)(ws + 64512352);   //    131,072
    bf16_t* Wth1  = (bf16_t*)(ws + 64643424);   //    131,072
    bf16_t* Wtl1  = (bf16_t*)(ws + 64774496);   //    131,072
    bf16_t* Wth2  = (bf16_t*)(ws + 64905568);   //     16,384
    bf16_t* Wtl2  = (bf16_t*)(ws + 64921952);   //     16,384 -> end 64,938,336

    const int NB = (N_NODES + 255) / 256;       // 196

    hipMemsetAsync(cnts,   0, N_NODES * sizeof(int), stream);
    hipMemsetAsync(cursor, 0, N_NODES * sizeof(int), stream);
    hipMemsetAsync((char*)meta + (size_t)E_TOT * 8, 0, 32, stream);  // pad

    k_hist     <<<(E_TOT + 255) / 256, 256, 0, stream>>>(ei, cnts);
    k_scan1    <<<NB, 256, 0, stream>>>(cnts, offs, bsum);
    k_scan2    <<<1, 256, 0, stream>>>(bsum, NB);
    k_scan3    <<<NB, 256, 0, stream>>>(offs, bsum);
    k_scatter  <<<(E_TOT + 255) / 256, 256, 0, stream>>>(ei, offs, cursor, srcs);
    k_split_all<<<544, 256, 0, stream>>>(W0, W1, W2, Wth0, Wtl0, Wth1, Wtl1, Wth2, Wtl2);

    const int AGG_BLOCKS = (N_NODES + 3) / 4;   // 12500

    // layer 0 (A = x fp32, in-register hi/lo split; W0 hi-only, LDS-resident)
    k_gemm256_reg<true><<<N_TILES128, 512, 0, stream>>>(x, nullptr, Wth0, as0, ad0, hA_b, As, Ad);
    k_attn<<<AGG_BLOCKS, 256, 0, stream>>>(As, Ad, offs, cnts, srcs, meta, inv);
    k_gather256<<<AGG_BLOCKS, 256, 0, stream>>>(hA_b, meta, offs, cnts, inv, b0, hB_b);
    // layer 1 (A exact bf16; W1 hi-only, LDS-resident)
    k_gemm256_reg<false><<<N_TILES128, 512, 0, stream>>>(nullptr, hB_b, Wth1, as1, ad1, hA_b, As, Ad);
    k_attn<<<AGG_BLOCKS, 256, 0, stream>>>(As, Ad, offs, cnts, srcs, meta, inv);
    k_gather256<<<AGG_BLOCKS, 256, 0, stream>>>(hA_b, meta, offs, cnts, inv, b1, hB_b);
    // layer 2 (+ fused log_softmax; W2 keeps hi+lo)
    k_gemm32_mfma<<<NB, 256, 0, stream>>>(hB_b, Wth2, Wtl2, as2, ad2, hC, As, Ad);
    k_attn<<<AGG_BLOCKS, 256, 0, stream>>>(As, Ad, offs, cnts, srcs, meta, inv);
    k_gather_final<<<AGG_BLOCKS, 256, 0, stream>>>(hC, meta, offs, cnts, inv, b2, out);
}